// Round 1
// baseline (1006.724 us; speedup 1.0000x reference)
//
#include <hip/hip_runtime.h>
#include <hip/hip_fp16.h>

#define N_IDS      600001
#define TAB_STRIDE 600016          // padded element stride
#define TAU        0.90f
#define BM_WORDS   9376            // ceil(ceil(600001/2)/32): 1 bit per bin-pair

// Native clang vector types (accepted by __builtin_nontemporal_*)
typedef int   v4i __attribute__((ext_vector_type(4)));
typedef float v4f __attribute__((ext_vector_type(4)));

// Interleaved table: tt[2*id] = t0[id], tt[2*id+1] = t1[id].
// Float atomic-max via int compare: valid (all values >= 0, init 0).
__device__ __forceinline__ void amax0(float* __restrict__ tt, int id, float v) {
    atomicMax((int*)(tt + 2 * id), __float_as_int(v));
}
__device__ __forceinline__ void amax1(float* __restrict__ tt, int id, float v) {
    atomicMax((int*)(tt + 2 * id + 1), __float_as_int(v));
}

// ---------------- Pass A: all loads unconditional + upfront (max MLP) -------
// Old version loaded feat, branched, then loaded pp -> two dependent memory
// round-trips per iteration. New: 6 independent 16B loads issued together;
// atomics predicated per element (~10% lanes).
__global__ __launch_bounds__(256) void pass_a_kernel(
    const v4i* __restrict__ pp4, const v4f* __restrict__ feat4,
    float* __restrict__ tt, float tau, int n8)
{
    int j = blockIdx.x * blockDim.x + threadIdx.x;
    if (j >= n8) return;
    v4f f0 = feat4[2 * j];
    v4f f1 = feat4[2 * j + 1];
    v4i a = pp4[4 * j];
    v4i b = pp4[4 * j + 1];
    v4i c = pp4[4 * j + 2];
    v4i d = pp4[4 * j + 3];
    if (f0.x >= tau) { amax0(tt, a.x, f0.x); amax1(tt, a.y, f0.x); }
    if (f0.y >= tau) { amax0(tt, a.z, f0.y); amax1(tt, a.w, f0.y); }
    if (f0.z >= tau) { amax0(tt, b.x, f0.z); amax1(tt, b.y, f0.z); }
    if (f0.w >= tau) { amax0(tt, b.z, f0.w); amax1(tt, b.w, f0.w); }
    if (f1.x >= tau) { amax0(tt, c.x, f1.x); amax1(tt, c.y, f1.x); }
    if (f1.y >= tau) { amax0(tt, c.z, f1.y); amax1(tt, c.w, f1.y); }
    if (f1.z >= tau) { amax0(tt, d.x, f1.z); amax1(tt, d.y, f1.z); }
    if (f1.w >= tau) { amax0(tt, d.z, f1.w); amax1(tt, d.w, f1.w); }
}

// ---------------- Bitmap: ballot, 1 thread per bin-pair ---------------------
__global__ __launch_bounds__(256) void bitmap_kernel(
    const float* __restrict__ tt, unsigned* __restrict__ bm)
{
    int p = blockIdx.x * blockDim.x + threadIdx.x;   // pair index (bins 2p,2p+1)
    bool open = false;
    if (p < BM_WORDS * 32) {
        // 4 contiguous entries: t0[2p], t1[2p], t0[2p+1], t1[2p+1]
        const v4f e = *(const v4f*)(tt + 4 * (size_t)p);
        open = (e.x < TAU) || (e.y < TAU) || (e.z < TAU) || (e.w < TAU);
    }
    unsigned long long m = __ballot(open);
    int lane = p & 63;
    if (lane == 0)  bm[p >> 5] = (unsigned)m;
    if (lane == 32) bm[p >> 5] = (unsigned)(m >> 32);
}

// ---------------- Pass B: LDS-bitmap filtered, 16 elems/iter ----------------
__device__ __forceinline__ bool open_bit(const unsigned* lbm, int id) {
    int bi = id >> 1;
    return (lbm[bi >> 5] >> (bi & 31)) & 1u;
}

__device__ __forceinline__ void pb_upd(const unsigned* lbm, float* __restrict__ tt,
                                       int id0, int id1, float v)
{
    if (v < TAU) {                      // v >= TAU fully handled by pass A
        if (open_bit(lbm, id0)) amax0(tt, id0, v);
        if (open_bit(lbm, id1)) amax1(tt, id1, v);
    }
}

__global__ __launch_bounds__(256) void pass_b_kernel(
    const v4i* __restrict__ pp4, const v4f* __restrict__ feat4,
    float* __restrict__ tt, const unsigned* __restrict__ bm, int n16)
{
    __shared__ unsigned lbm[BM_WORDS];  // 37.5 KB -> 4 blocks/CU
    for (int w = threadIdx.x; w < BM_WORDS; w += 256) lbm[w] = bm[w];
    __syncthreads();
    int stride = gridDim.x * blockDim.x;
    for (int g = blockIdx.x * blockDim.x + threadIdx.x; g < n16; g += stride) {
        // Issue all 12 loads up front (independent -> max MLP)
        v4f f0 = feat4[4 * g];
        v4f f1 = feat4[4 * g + 1];
        v4f f2 = feat4[4 * g + 2];
        v4f f3 = feat4[4 * g + 3];
        v4i p0 = pp4[8 * g];
        v4i p1 = pp4[8 * g + 1];
        v4i p2 = pp4[8 * g + 2];
        v4i p3 = pp4[8 * g + 3];
        v4i p4 = pp4[8 * g + 4];
        v4i p5 = pp4[8 * g + 5];
        v4i p6 = pp4[8 * g + 6];
        v4i p7 = pp4[8 * g + 7];
        pb_upd(lbm, tt, p0.x, p0.y, f0.x); pb_upd(lbm, tt, p0.z, p0.w, f0.y);
        pb_upd(lbm, tt, p1.x, p1.y, f0.z); pb_upd(lbm, tt, p1.z, p1.w, f0.w);
        pb_upd(lbm, tt, p2.x, p2.y, f1.x); pb_upd(lbm, tt, p2.z, p2.w, f1.y);
        pb_upd(lbm, tt, p3.x, p3.y, f1.z); pb_upd(lbm, tt, p3.z, p3.w, f1.w);
        pb_upd(lbm, tt, p4.x, p4.y, f2.x); pb_upd(lbm, tt, p4.z, p4.w, f2.y);
        pb_upd(lbm, tt, p5.x, p5.y, f2.z); pb_upd(lbm, tt, p5.z, p5.w, f2.w);
        pb_upd(lbm, tt, p6.x, p6.y, f3.x); pb_upd(lbm, tt, p6.z, p6.w, f3.y);
        pb_upd(lbm, tt, p7.x, p7.y, f3.z); pb_upd(lbm, tt, p7.z, p7.w, f3.w);
    }
}

// ---------------- Pack interleaved fp32 table to half2 ---------------------
__global__ __launch_bounds__(256) void pack_kernel(
    const float* __restrict__ tt, __half2* __restrict__ hh)
{
    int i = blockIdx.x * blockDim.x + threadIdx.x;
    if (i < N_IDS) {
        const float* e = tt + 2 * (size_t)i;
        hh[i] = __floats2half2_rn(e[0], e[1]);   // (t0[i], t1[i])
    }
}

// ---------------- Gather A/B experiment -------------------------------------
// Theory: gather is L1-miss (MSHR) bound; table gathers have ~1.4% L1 hit rate
// so L1 allocation is pure overhead. Half the range runs plain gathers, half
// runs nontemporal (L1-bypass) gathers -> per-dispatch rocprof rows give a
// within-launch A/B. Risk: if nt also no-allocates in L2, the nt half slows
// ~2x (gathers degrade to L3) -> revert next round.

__device__ __forceinline__ __half2 ld_nt_h2(const __half2* p) {
    union { unsigned u; __half2 h; } cv;
    cv.u = __builtin_nontemporal_load((const unsigned*)p);
    return cv.h;
}

__global__ __launch_bounds__(256) void gather_l1_kernel(
    const v4i* __restrict__ pp4, const __half2* __restrict__ hh,
    v4f* __restrict__ out4, int jbase, int jend)
{
    int j = jbase + blockIdx.x * blockDim.x + threadIdx.x;
    if (j >= jend) return;
    v4i a = __builtin_nontemporal_load(&pp4[4 * j]);
    v4i b = __builtin_nontemporal_load(&pp4[4 * j + 1]);
    v4i c = __builtin_nontemporal_load(&pp4[4 * j + 2]);
    v4i d = __builtin_nontemporal_load(&pp4[4 * j + 3]);
    __half2 g0 = hh[a.x], g1 = hh[a.y], g2 = hh[a.z], g3 = hh[a.w];
    __half2 g4 = hh[b.x], g5 = hh[b.y], g6 = hh[b.z], g7 = hh[b.w];
    __half2 g8 = hh[c.x], g9 = hh[c.y], ga = hh[c.z], gb = hh[c.w];
    __half2 gc = hh[d.x], gd = hh[d.y], ge = hh[d.z], gf = hh[d.w];
    v4f o0, o1;
    o0.x = __half2float(__low2half(g0)) * __half2float(__high2half(g1));
    o0.y = __half2float(__low2half(g2)) * __half2float(__high2half(g3));
    o0.z = __half2float(__low2half(g4)) * __half2float(__high2half(g5));
    o0.w = __half2float(__low2half(g6)) * __half2float(__high2half(g7));
    o1.x = __half2float(__low2half(g8)) * __half2float(__high2half(g9));
    o1.y = __half2float(__low2half(ga)) * __half2float(__high2half(gb));
    o1.z = __half2float(__low2half(gc)) * __half2float(__high2half(gd));
    o1.w = __half2float(__low2half(ge)) * __half2float(__high2half(gf));
    __builtin_nontemporal_store(o0, &out4[2 * j]);
    __builtin_nontemporal_store(o1, &out4[2 * j + 1]);
}

__global__ __launch_bounds__(256) void gather_nt_kernel(
    const v4i* __restrict__ pp4, const __half2* __restrict__ hh,
    v4f* __restrict__ out4, int jbase, int jend)
{
    int j = jbase + blockIdx.x * blockDim.x + threadIdx.x;
    if (j >= jend) return;
    v4i a = __builtin_nontemporal_load(&pp4[4 * j]);
    v4i b = __builtin_nontemporal_load(&pp4[4 * j + 1]);
    v4i c = __builtin_nontemporal_load(&pp4[4 * j + 2]);
    v4i d = __builtin_nontemporal_load(&pp4[4 * j + 3]);
    __half2 g0 = ld_nt_h2(&hh[a.x]), g1 = ld_nt_h2(&hh[a.y]);
    __half2 g2 = ld_nt_h2(&hh[a.z]), g3 = ld_nt_h2(&hh[a.w]);
    __half2 g4 = ld_nt_h2(&hh[b.x]), g5 = ld_nt_h2(&hh[b.y]);
    __half2 g6 = ld_nt_h2(&hh[b.z]), g7 = ld_nt_h2(&hh[b.w]);
    __half2 g8 = ld_nt_h2(&hh[c.x]), g9 = ld_nt_h2(&hh[c.y]);
    __half2 ga = ld_nt_h2(&hh[c.z]), gb = ld_nt_h2(&hh[c.w]);
    __half2 gc = ld_nt_h2(&hh[d.x]), gd = ld_nt_h2(&hh[d.y]);
    __half2 ge = ld_nt_h2(&hh[d.z]), gf = ld_nt_h2(&hh[d.w]);
    v4f o0, o1;
    o0.x = __half2float(__low2half(g0)) * __half2float(__high2half(g1));
    o0.y = __half2float(__low2half(g2)) * __half2float(__high2half(g3));
    o0.z = __half2float(__low2half(g4)) * __half2float(__high2half(g5));
    o0.w = __half2float(__low2half(g6)) * __half2float(__high2half(g7));
    o1.x = __half2float(__low2half(g8)) * __half2float(__high2half(g9));
    o1.y = __half2float(__low2half(ga)) * __half2float(__high2half(gb));
    o1.z = __half2float(__low2half(gc)) * __half2float(__high2half(gd));
    o1.w = __half2float(__low2half(ge)) * __half2float(__high2half(gf));
    __builtin_nontemporal_store(o0, &out4[2 * j]);
    __builtin_nontemporal_store(o1, &out4[2 * j + 1]);
}

// ---------------- Defensive scalar tails (n = 2^25 -> unused) ---------------
__global__ void tail_scatter_kernel(const int* __restrict__ pp,
                                    const float* __restrict__ feat,
                                    float* __restrict__ tt, int start, int n)
{
    int i = start + blockIdx.x * blockDim.x + threadIdx.x;
    if (i >= n) return;
    float v = feat[i];
    amax0(tt, pp[2 * i], v);
    amax1(tt, pp[2 * i + 1], v);
}

__global__ void tail_gather_kernel(const int* __restrict__ pp,
                                   const __half2* __restrict__ hh,
                                   float* __restrict__ out, int start, int n)
{
    int i = start + blockIdx.x * blockDim.x + threadIdx.x;
    if (i >= n) return;
    out[i] = __half2float(__low2half(hh[pp[2 * i]])) *
             __half2float(__high2half(hh[pp[2 * i + 1]]));
}

extern "C" void kernel_launch(void* const* d_in, const int* in_sizes, int n_in,
                              void* d_out, int out_size, void* d_ws, size_t ws_size,
                              hipStream_t stream) {
    const int*   pp   = (const int*)d_in[0];    // (n,2) int32, interleaved
    const float* feat = (const float*)d_in[1];  // (n,) float32
    float* out = (float*)d_out;
    int n = in_sizes[1];

    // ws layout: [tt: 2*TAB_STRIDE f32][bm: BM_WORDS u32][hh: TAB_STRIDE half2]
    float* tt = (float*)d_ws;
    size_t tt_bytes = 2 * (size_t)TAB_STRIDE * sizeof(float);      // 4,800,128
    unsigned* bm = (unsigned*)((char*)d_ws + tt_bytes);
    __half2* hh = (__half2*)((char*)d_ws + tt_bytes + BM_WORDS * sizeof(unsigned));

    (void)hipMemsetAsync(d_ws, 0, tt_bytes, stream);  // tables start at 0

    int n8 = n / 8;
    int n16 = n / 16;
    int tail_start = n8 * 8;
    dim3 block(256);
    dim3 gridA((n8 + 255) / 256);

    // Pass A: only v >= TAU issues atomics (~10% of updates)
    pass_a_kernel<<<gridA, block, 0, stream>>>(
        (const v4i*)pp, (const v4f*)feat, tt, TAU, n8);
    if (tail_start < n) {
        int t = n - tail_start;
        tail_scatter_kernel<<<(t + 255) / 256, 256, 0, stream>>>(
            pp, feat, tt, tail_start, n);
    }
    // Bitmap of still-open bin-pairs
    bitmap_kernel<<<(BM_WORDS * 32 + 255) / 256, 256, 0, stream>>>(tt, bm);
    // Pass B: LDS-bitmap-filtered atomics for v < TAU (~1-2% issue)
    pass_b_kernel<<<1024, block, 0, stream>>>(
        (const v4i*)pp, (const v4f*)feat, tt, bm, n16);
    // Pack to half2
    pack_kernel<<<(N_IDS + 255) / 256, 256, 0, stream>>>(tt, hh);
    // Gather A/B: first half with L1-cached table gathers, second half with
    // nontemporal (L1-bypass) table gathers. Per-dispatch rocprof rows give
    // the within-launch comparison.
    int nh = n8 / 2;
    if (nh > 0) {
        gather_l1_kernel<<<(nh + 255) / 256, block, 0, stream>>>(
            (const v4i*)pp, hh, (v4f*)out, 0, nh);
    }
    if (n8 - nh > 0) {
        gather_nt_kernel<<<(n8 - nh + 255) / 256, block, 0, stream>>>(
            (const v4i*)pp, hh, (v4f*)out, nh, n8);
    }
    if (tail_start < n) {
        int t = n - tail_start;
        tail_gather_kernel<<<(t + 255) / 256, 256, 0, stream>>>(
            pp, hh, out, tail_start, n);
    }
}

// Round 2
// 1001.605 us; speedup vs baseline: 1.0051x; 1.0051x over previous
//
#include <hip/hip_runtime.h>
#include <hip/hip_fp16.h>

#define N_IDS      600001
#define TAB_STRIDE 600016          // padded element stride
#define TAU        0.90f
#define BM_WORDS   9376            // ceil(ceil(600001/2)/32): 1 bit per bin-pair

// Native clang vector types (accepted by __builtin_nontemporal_*)
typedef int   v4i __attribute__((ext_vector_type(4)));
typedef float v4f __attribute__((ext_vector_type(4)));

// Interleaved table: tt[2*id] = t0[id], tt[2*id+1] = t1[id].
// Float atomic-max via int compare: valid (all values >= 0, init 0).
__device__ __forceinline__ void amax0(float* __restrict__ tt, int id, float v) {
    atomicMax((int*)(tt + 2 * id), __float_as_int(v));
}
__device__ __forceinline__ void amax1(float* __restrict__ tt, int id, float v) {
    atomicMax((int*)(tt + 2 * id + 1), __float_as_int(v));
}

// ---------------- Pass A: all loads unconditional + upfront (max MLP) -------
// Old version loaded feat, branched, then loaded pp -> two dependent memory
// round-trips per iteration. New: 6 independent 16B loads issued together;
// atomics predicated per element (~10% lanes).
__global__ __launch_bounds__(256) void pass_a_kernel(
    const v4i* __restrict__ pp4, const v4f* __restrict__ feat4,
    float* __restrict__ tt, float tau, int n8)
{
    int j = blockIdx.x * blockDim.x + threadIdx.x;
    if (j >= n8) return;
    v4f f0 = feat4[2 * j];
    v4f f1 = feat4[2 * j + 1];
    v4i a = pp4[4 * j];
    v4i b = pp4[4 * j + 1];
    v4i c = pp4[4 * j + 2];
    v4i d = pp4[4 * j + 3];
    if (f0.x >= tau) { amax0(tt, a.x, f0.x); amax1(tt, a.y, f0.x); }
    if (f0.y >= tau) { amax0(tt, a.z, f0.y); amax1(tt, a.w, f0.y); }
    if (f0.z >= tau) { amax0(tt, b.x, f0.z); amax1(tt, b.y, f0.z); }
    if (f0.w >= tau) { amax0(tt, b.z, f0.w); amax1(tt, b.w, f0.w); }
    if (f1.x >= tau) { amax0(tt, c.x, f1.x); amax1(tt, c.y, f1.x); }
    if (f1.y >= tau) { amax0(tt, c.z, f1.y); amax1(tt, c.w, f1.y); }
    if (f1.z >= tau) { amax0(tt, d.x, f1.z); amax1(tt, d.y, f1.z); }
    if (f1.w >= tau) { amax0(tt, d.z, f1.w); amax1(tt, d.w, f1.w); }
}

// ---------------- Bitmap: ballot, 1 thread per bin-pair ---------------------
__global__ __launch_bounds__(256) void bitmap_kernel(
    const float* __restrict__ tt, unsigned* __restrict__ bm)
{
    int p = blockIdx.x * blockDim.x + threadIdx.x;   // pair index (bins 2p,2p+1)
    bool open = false;
    if (p < BM_WORDS * 32) {
        // 4 contiguous entries: t0[2p], t1[2p], t0[2p+1], t1[2p+1]
        const v4f e = *(const v4f*)(tt + 4 * (size_t)p);
        open = (e.x < TAU) || (e.y < TAU) || (e.z < TAU) || (e.w < TAU);
    }
    unsigned long long m = __ballot(open);
    int lane = p & 63;
    if (lane == 0)  bm[p >> 5] = (unsigned)m;
    if (lane == 32) bm[p >> 5] = (unsigned)(m >> 32);
}

// ---------------- Pass B: LDS-bitmap filtered, 16 elems/iter ----------------
__device__ __forceinline__ bool open_bit(const unsigned* lbm, int id) {
    int bi = id >> 1;
    return (lbm[bi >> 5] >> (bi & 31)) & 1u;
}

__device__ __forceinline__ void pb_upd(const unsigned* lbm, float* __restrict__ tt,
                                       int id0, int id1, float v)
{
    if (v < TAU) {                      // v >= TAU fully handled by pass A
        if (open_bit(lbm, id0)) amax0(tt, id0, v);
        if (open_bit(lbm, id1)) amax1(tt, id1, v);
    }
}

__global__ __launch_bounds__(256) void pass_b_kernel(
    const v4i* __restrict__ pp4, const v4f* __restrict__ feat4,
    float* __restrict__ tt, const unsigned* __restrict__ bm, int n16)
{
    __shared__ unsigned lbm[BM_WORDS];  // 37.5 KB -> 4 blocks/CU
    for (int w = threadIdx.x; w < BM_WORDS; w += 256) lbm[w] = bm[w];
    __syncthreads();
    int stride = gridDim.x * blockDim.x;
    for (int g = blockIdx.x * blockDim.x + threadIdx.x; g < n16; g += stride) {
        // Issue all 12 loads up front (independent -> max MLP)
        v4f f0 = feat4[4 * g];
        v4f f1 = feat4[4 * g + 1];
        v4f f2 = feat4[4 * g + 2];
        v4f f3 = feat4[4 * g + 3];
        v4i p0 = pp4[8 * g];
        v4i p1 = pp4[8 * g + 1];
        v4i p2 = pp4[8 * g + 2];
        v4i p3 = pp4[8 * g + 3];
        v4i p4 = pp4[8 * g + 4];
        v4i p5 = pp4[8 * g + 5];
        v4i p6 = pp4[8 * g + 6];
        v4i p7 = pp4[8 * g + 7];
        pb_upd(lbm, tt, p0.x, p0.y, f0.x); pb_upd(lbm, tt, p0.z, p0.w, f0.y);
        pb_upd(lbm, tt, p1.x, p1.y, f0.z); pb_upd(lbm, tt, p1.z, p1.w, f0.w);
        pb_upd(lbm, tt, p2.x, p2.y, f1.x); pb_upd(lbm, tt, p2.z, p2.w, f1.y);
        pb_upd(lbm, tt, p3.x, p3.y, f1.z); pb_upd(lbm, tt, p3.z, p3.w, f1.w);
        pb_upd(lbm, tt, p4.x, p4.y, f2.x); pb_upd(lbm, tt, p4.z, p4.w, f2.y);
        pb_upd(lbm, tt, p5.x, p5.y, f2.z); pb_upd(lbm, tt, p5.z, p5.w, f2.w);
        pb_upd(lbm, tt, p6.x, p6.y, f3.x); pb_upd(lbm, tt, p6.z, p6.w, f3.y);
        pb_upd(lbm, tt, p7.x, p7.y, f3.z); pb_upd(lbm, tt, p7.z, p7.w, f3.w);
    }
}

// ---------------- Pack interleaved fp32 table to half2 ---------------------
__global__ __launch_bounds__(256) void pack_kernel(
    const float* __restrict__ tt, __half2* __restrict__ hh)
{
    int i = blockIdx.x * blockDim.x + threadIdx.x;
    if (i < N_IDS) {
        const float* e = tt + 2 * (size_t)i;
        hh[i] = __floats2half2_rn(e[0], e[1]);   // (t0[i], t1[i])
    }
}

// ---------------- Gather A/B experiment -------------------------------------
// Theory: gather is L1-miss (MSHR) bound; table gathers have ~1.4% L1 hit rate
// so L1 allocation is pure overhead. Half the range runs plain gathers, half
// runs nontemporal (L1-bypass) gathers -> per-dispatch rocprof rows give a
// within-launch A/B. Risk: if nt also no-allocates in L2, the nt half slows
// ~2x (gathers degrade to L3) -> revert next round.

__device__ __forceinline__ __half2 ld_nt_h2(const __half2* p) {
    union { unsigned u; __half2 h; } cv;
    cv.u = __builtin_nontemporal_load((const unsigned*)p);
    return cv.h;
}

__global__ __launch_bounds__(256) void gather_l1_kernel(
    const v4i* __restrict__ pp4, const __half2* __restrict__ hh,
    v4f* __restrict__ out4, int jbase, int jend)
{
    int j = jbase + blockIdx.x * blockDim.x + threadIdx.x;
    if (j >= jend) return;
    v4i a = __builtin_nontemporal_load(&pp4[4 * j]);
    v4i b = __builtin_nontemporal_load(&pp4[4 * j + 1]);
    v4i c = __builtin_nontemporal_load(&pp4[4 * j + 2]);
    v4i d = __builtin_nontemporal_load(&pp4[4 * j + 3]);
    __half2 g0 = hh[a.x], g1 = hh[a.y], g2 = hh[a.z], g3 = hh[a.w];
    __half2 g4 = hh[b.x], g5 = hh[b.y], g6 = hh[b.z], g7 = hh[b.w];
    __half2 g8 = hh[c.x], g9 = hh[c.y], ga = hh[c.z], gb = hh[c.w];
    __half2 gc = hh[d.x], gd = hh[d.y], ge = hh[d.z], gf = hh[d.w];
    v4f o0, o1;
    o0.x = __half2float(__low2half(g0)) * __half2float(__high2half(g1));
    o0.y = __half2float(__low2half(g2)) * __half2float(__high2half(g3));
    o0.z = __half2float(__low2half(g4)) * __half2float(__high2half(g5));
    o0.w = __half2float(__low2half(g6)) * __half2float(__high2half(g7));
    o1.x = __half2float(__low2half(g8)) * __half2float(__high2half(g9));
    o1.y = __half2float(__low2half(ga)) * __half2float(__high2half(gb));
    o1.z = __half2float(__low2half(gc)) * __half2float(__high2half(gd));
    o1.w = __half2float(__low2half(ge)) * __half2float(__high2half(gf));
    __builtin_nontemporal_store(o0, &out4[2 * j]);
    __builtin_nontemporal_store(o1, &out4[2 * j + 1]);
}

__global__ __launch_bounds__(256) void gather_nt_kernel(
    const v4i* __restrict__ pp4, const __half2* __restrict__ hh,
    v4f* __restrict__ out4, int jbase, int jend)
{
    int j = jbase + blockIdx.x * blockDim.x + threadIdx.x;
    if (j >= jend) return;
    v4i a = __builtin_nontemporal_load(&pp4[4 * j]);
    v4i b = __builtin_nontemporal_load(&pp4[4 * j + 1]);
    v4i c = __builtin_nontemporal_load(&pp4[4 * j + 2]);
    v4i d = __builtin_nontemporal_load(&pp4[4 * j + 3]);
    __half2 g0 = ld_nt_h2(&hh[a.x]), g1 = ld_nt_h2(&hh[a.y]);
    __half2 g2 = ld_nt_h2(&hh[a.z]), g3 = ld_nt_h2(&hh[a.w]);
    __half2 g4 = ld_nt_h2(&hh[b.x]), g5 = ld_nt_h2(&hh[b.y]);
    __half2 g6 = ld_nt_h2(&hh[b.z]), g7 = ld_nt_h2(&hh[b.w]);
    __half2 g8 = ld_nt_h2(&hh[c.x]), g9 = ld_nt_h2(&hh[c.y]);
    __half2 ga = ld_nt_h2(&hh[c.z]), gb = ld_nt_h2(&hh[c.w]);
    __half2 gc = ld_nt_h2(&hh[d.x]), gd = ld_nt_h2(&hh[d.y]);
    __half2 ge = ld_nt_h2(&hh[d.z]), gf = ld_nt_h2(&hh[d.w]);
    v4f o0, o1;
    o0.x = __half2float(__low2half(g0)) * __half2float(__high2half(g1));
    o0.y = __half2float(__low2half(g2)) * __half2float(__high2half(g3));
    o0.z = __half2float(__low2half(g4)) * __half2float(__high2half(g5));
    o0.w = __half2float(__low2half(g6)) * __half2float(__high2half(g7));
    o1.x = __half2float(__low2half(g8)) * __half2float(__high2half(g9));
    o1.y = __half2float(__low2half(ga)) * __half2float(__high2half(gb));
    o1.z = __half2float(__low2half(gc)) * __half2float(__high2half(gd));
    o1.w = __half2float(__low2half(ge)) * __half2float(__high2half(gf));
    __builtin_nontemporal_store(o0, &out4[2 * j]);
    __builtin_nontemporal_store(o1, &out4[2 * j + 1]);
}

// ---------------- Defensive scalar tails (n = 2^25 -> unused) ---------------
__global__ void tail_scatter_kernel(const int* __restrict__ pp,
                                    const float* __restrict__ feat,
                                    float* __restrict__ tt, int start, int n)
{
    int i = start + blockIdx.x * blockDim.x + threadIdx.x;
    if (i >= n) return;
    float v = feat[i];
    amax0(tt, pp[2 * i], v);
    amax1(tt, pp[2 * i + 1], v);
}

__global__ void tail_gather_kernel(const int* __restrict__ pp,
                                   const __half2* __restrict__ hh,
                                   float* __restrict__ out, int start, int n)
{
    int i = start + blockIdx.x * blockDim.x + threadIdx.x;
    if (i >= n) return;
    out[i] = __half2float(__low2half(hh[pp[2 * i]])) *
             __half2float(__high2half(hh[pp[2 * i + 1]]));
}

extern "C" void kernel_launch(void* const* d_in, const int* in_sizes, int n_in,
                              void* d_out, int out_size, void* d_ws, size_t ws_size,
                              hipStream_t stream) {
    const int*   pp   = (const int*)d_in[0];    // (n,2) int32, interleaved
    const float* feat = (const float*)d_in[1];  // (n,) float32
    float* out = (float*)d_out;
    int n = in_sizes[1];

    // ws layout: [tt: 2*TAB_STRIDE f32][bm: BM_WORDS u32][hh: TAB_STRIDE half2]
    float* tt = (float*)d_ws;
    size_t tt_bytes = 2 * (size_t)TAB_STRIDE * sizeof(float);      // 4,800,128
    unsigned* bm = (unsigned*)((char*)d_ws + tt_bytes);
    __half2* hh = (__half2*)((char*)d_ws + tt_bytes + BM_WORDS * sizeof(unsigned));

    (void)hipMemsetAsync(d_ws, 0, tt_bytes, stream);  // tables start at 0

    int n8 = n / 8;
    int n16 = n / 16;
    int tail_start = n8 * 8;
    dim3 block(256);
    dim3 gridA((n8 + 255) / 256);

    // Pass A: only v >= TAU issues atomics (~10% of updates)
    pass_a_kernel<<<gridA, block, 0, stream>>>(
        (const v4i*)pp, (const v4f*)feat, tt, TAU, n8);
    if (tail_start < n) {
        int t = n - tail_start;
        tail_scatter_kernel<<<(t + 255) / 256, 256, 0, stream>>>(
            pp, feat, tt, tail_start, n);
    }
    // Bitmap of still-open bin-pairs
    bitmap_kernel<<<(BM_WORDS * 32 + 255) / 256, 256, 0, stream>>>(tt, bm);
    // Pass B: LDS-bitmap-filtered atomics for v < TAU (~1-2% issue)
    pass_b_kernel<<<1024, block, 0, stream>>>(
        (const v4i*)pp, (const v4f*)feat, tt, bm, n16);
    // Pack to half2
    pack_kernel<<<(N_IDS + 255) / 256, 256, 0, stream>>>(tt, hh);
    // Gather A/B: first half with L1-cached table gathers, second half with
    // nontemporal (L1-bypass) table gathers. Per-dispatch rocprof rows give
    // the within-launch comparison.
    int nh = n8 / 2;
    if (nh > 0) {
        gather_l1_kernel<<<(nh + 255) / 256, block, 0, stream>>>(
            (const v4i*)pp, hh, (v4f*)out, 0, nh);
    }
    if (n8 - nh > 0) {
        gather_nt_kernel<<<(n8 - nh + 255) / 256, block, 0, stream>>>(
            (const v4i*)pp, hh, (v4f*)out, nh, n8);
    }
    if (tail_start < n) {
        int t = n - tail_start;
        tail_gather_kernel<<<(t + 255) / 256, 256, 0, stream>>>(
            pp, hh, out, tail_start, n);
    }
}